// Round 2
// baseline (303.675 us; speedup 1.0000x reference)
//
#include <hip/hip_runtime.h>
#include <hip/hip_fp16.h>
#include <stdint.h>

#define H_   256
#define W_   256
#define HW_  65536
#define NIMG 8

#define TI   32
#define TJ   64
#define HALO 10
#define RDI  52   // TI + 2*HALO
#define RDJ  84   // TJ + 2*HALO

typedef _Float16 half8_t __attribute__((ext_vector_type(8)));
typedef __fp16   fp16x2  __attribute__((ext_vector_type(2)));
typedef float    float4_t __attribute__((ext_vector_type(4)));

__device__ __forceinline__ uint32_t pk2(float a, float b) {
    fp16x2 h = __builtin_amdgcn_cvt_pkrtz(a, b);
    union { fp16x2 h; uint32_t u; } v; v.h = h; return v.u;
}
__device__ __forceinline__ __half2 u2h(uint32_t u) {
    union { uint32_t u; __half2 h; } v; v.u = u; return v.h;
}
__device__ __forceinline__ __half2 lerp2(__half2 p, __half2 q, __half2 f) {
    return __hfma2(f, __hsub2(q, p), p);
}

// ---------------- Kernel A: pointwise conv via MFMA f16, direct global loads ----------------
// (unchanged from R1 for attribution)
__global__ __launch_bounds__(256) void pw_off_kernel(
    const float* __restrict__ x, const float* __restrict__ pw,
    const float* __restrict__ offw, const float* __restrict__ offb,
    uint32_t* __restrict__ ypackI, float* __restrict__ sbuf)
{
    const int t    = threadIdx.x;
    const int blk  = blockIdx.x;          // 2048 blocks, 256 px each
    const int n    = blk >> 8;
    const int hw0  = (blk & 255) << 8;
    const int lane = t & 63;
    const int l15  = lane & 15;
    const int q    = lane >> 4;
    const int wv   = t >> 6;

    half8_t af[4][2];
    #pragma unroll
    for (int mt = 0; mt < 4; ++mt) {
        #pragma unroll
        for (int kt = 0; kt < 2; ++kt) {
            const float* wr = pw + (mt * 16 + l15) * 64 + kt * 32 + q * 8;
            float4 w0 = *(const float4*)wr;
            float4 w1 = *(const float4*)(wr + 4);
            union { uint32_t u[4]; half8_t h; } v;
            v.u[0] = pk2(w0.x, w0.y); v.u[1] = pk2(w0.z, w0.w);
            v.u[2] = pk2(w1.x, w1.y); v.u[3] = pk2(w1.z, w1.w);
            af[mt][kt] = v.h;
        }
    }
    float4_t ow4[4];
    #pragma unroll
    for (int mt = 0; mt < 4; ++mt)
        ow4[mt] = *(const float4_t*)(offw + mt * 16 + q * 4);
    const float bias = offb[0];

    #pragma unroll
    for (int j = 0; j < 4; ++j) {
        const int pix = (wv * 4 + j) * 16 + l15;
        const int hw  = hw0 + pix;
        const float* xp = x + (size_t)n * 64 * HW_ + hw;

        half8_t bf[2];
        #pragma unroll
        for (int kt = 0; kt < 2; ++kt) {
            const float* xk = xp + (size_t)(kt * 32 + q * 8) * HW_;
            float v0 = xk[0 * (size_t)HW_];
            float v1 = xk[1 * (size_t)HW_];
            float v2 = xk[2 * (size_t)HW_];
            float v3 = xk[3 * (size_t)HW_];
            float v4 = xk[4 * (size_t)HW_];
            float v5 = xk[5 * (size_t)HW_];
            float v6 = xk[6 * (size_t)HW_];
            float v7 = xk[7 * (size_t)HW_];
            union { uint32_t u[4]; half8_t h; } vv;
            vv.u[0] = pk2(v0, v1); vv.u[1] = pk2(v2, v3);
            vv.u[2] = pk2(v4, v5); vv.u[3] = pk2(v6, v7);
            bf[kt] = vv.h;
        }

        float4_t acc[4] = {{0,0,0,0},{0,0,0,0},{0,0,0,0},{0,0,0,0}};
        #pragma unroll
        for (int kt = 0; kt < 2; ++kt) {
            #pragma unroll
            for (int mt = 0; mt < 4; ++mt)
                acc[mt] = __builtin_amdgcn_mfma_f32_16x16x32_f16(af[mt][kt], bf[kt], acc[mt], 0, 0, 0);
        }

        float sp = 0.f;
        #pragma unroll
        for (int mt = 0; mt < 4; ++mt)
            sp += acc[mt][0] * ow4[mt][0] + acc[mt][1] * ow4[mt][1]
                + acc[mt][2] * ow4[mt][2] + acc[mt][3] * ow4[mt][3];
        sp += __shfl_xor(sp, 16, 64);
        sp += __shfl_xor(sp, 32, 64);
        float sv = fminf(fmaxf(sp + bias, 0.f), 8.f);
        if (q == 0) sbuf[(size_t)n * HW_ + hw] = sv;

        #pragma unroll
        for (int mt = 0; mt < 4; ++mt) {
            uint2 st;
            st.x = pk2(acc[mt][0], acc[mt][1]);
            st.y = pk2(acc[mt][2], acc[mt][3]);
            const int pg = mt * 2 + (q >> 1);
            size_t ad = (((size_t)(n * 8 + pg)) * HW_ + hw) * 4 + (q & 1) * 2;
            *(uint2*)&ypackI[ad] = st;
        }
    }
}

// ---------------- Kernel B: deformable depthwise 3x3, separable bilinear ----------------
// v3: (1) per-lane exec-masked reads: ~50% of pixels have s==0 (ReLU clip) -> the 16
//     "+1" row/col reads have exactly zero weight for those lanes; masking them off
//     thins the data-dependent LDS bank-conflict buckets.
//     (2) XCD chunk swizzle: each XCD owns 8 whole z-planes -> halo re-reads are L2-local.
//     (3) 3-way accumulator split (shorter fma chains).
__global__ __launch_bounds__(512) void deform_kernel(
    const uint4* __restrict__ ypackI, const float* __restrict__ sbuf,
    const float* __restrict__ dwp, float* __restrict__ out)
{
    __shared__ uint4 smem[RDI * RDJ];   // 69.9 KB -> 2 blocks/CU

    const int t  = threadIdx.x;
    const int b  = blockIdx.x;           // 2048 blocks, 1D
    // XCD chunk swizzle: XCD = b % 8 gets sb in [ (b%8)*256, (b%8)*256+256 )
    const int sb = (b & 7) * 256 + (b >> 3);
    const int z  = sb >> 5;              // 32 tiles per z-plane
    const int ti = (sb >> 2) & 7;        // 8 row-tiles
    const int tj = sb & 3;               // 4 col-tiles
    const int n  = z >> 3;
    const int pg = z & 7;
    const int i0 = ti * TI, j0 = tj * TJ;

    // ---- stage zero-padded interleaved region (rolled; frees VGPRs for mask code) ----
    const size_t ybase = (size_t)z * HW_;
    for (int idx = t; idx < RDI * RDJ; idx += 512) {
        int r  = idx / RDJ;
        int c  = idx - r * RDJ;
        int gr = i0 - HALO + r;
        int gc = j0 - HALO + c;
        bool ok = (gr >= 0) & (gr < H_) & (gc >= 0) & (gc < W_);
        uint4 v = {0u, 0u, 0u, 0u};
        if (ok) v = ypackI[ybase + gr * W_ + gc];
        smem[idx] = v;
    }

    // depthwise weights (uniform scalar loads), packed per channel-pair
    const int c0 = pg * 8;
    __half2 d2[4][9];
    #pragma unroll
    for (int pp = 0; pp < 4; ++pp) {
        #pragma unroll
        for (int k = 0; k < 9; ++k)
            d2[pp][k] = __floats2half2_rn(dwp[(c0 + 2 * pp) * 9 + k],
                                          dwp[(c0 + 2 * pp + 1) * 9 + k]);
    }
    __syncthreads();

    const int lj = t & 63;      // column within tile 0..63
    const int l8 = t >> 6;      // wave row 0..7

    #pragma unroll
    for (int qq = 0; qq < 4; ++qq) {
        const int li = l8 + qq * 8;           // 0..31
        const int gi = i0 + li, gj = j0 + lj;
        const float sv = sbuf[(size_t)n * HW_ + gi * W_ + gj];
        // s==0 (or s==8): all fractional weights are exactly 0 -> the 16 "+1" reads
        // are dead weight; mask them off per-lane to thin LDS bank traffic.
        const bool act = (sv > 0.0f) & (sv < 8.0f);
        const float tt = 1.0f + sv;
        const float lr = (float)(li + HALO);
        const float lc = (float)(lj + HALO);
        const int ra0 = (int)floorf(lr - tt); const float fya = (lr - tt) - (float)ra0;
        const int rb0 = (int)floorf(lr + tt); const float fyb = (lr + tt) - (float)rb0;
        const int ca0 = (int)floorf(lc - tt); const float fxa = (lc - tt) - (float)ca0;
        const int cb0 = (int)floorf(lc + tt); const float fxb = (lc + tt) - (float)cb0;
        const int rc = li + HALO, cc = lj + HALO;
        const __half2 fxa2 = __float2half2_rn(fxa);
        const __half2 fxb2 = __float2half2_rn(fxb);
        const __half2 fya2 = __float2half2_rn(fya);
        const __half2 fyb2 = __float2half2_rn(fyb);

        __half2 A0[4], C0[4], B0[4], A1[4], C1[4], B1[4];

// ALW is a compile-time literal: 1 = row always needed, 0 = row weight ~ frac (mask by act).
// Masked-off lanes keep zeros; all lerps degenerate correctly since their frac weight is 0.
#define LOADCOLS(ro, ALW, Av, Cv, Bv) do {                              \
        uint4 v0 = {0u,0u,0u,0u}, v1 = {0u,0u,0u,0u}, vc = {0u,0u,0u,0u}; \
        uint4 v3 = {0u,0u,0u,0u}, v4 = {0u,0u,0u,0u};                   \
        if (ALW) {                                                      \
            v0 = smem[(ro) + ca0]; vc = smem[(ro) + cc]; v3 = smem[(ro) + cb0]; \
            if (act) { v1 = smem[(ro) + ca0 + 1]; v4 = smem[(ro) + cb0 + 1]; } \
        } else if (act) {                                               \
            v0 = smem[(ro) + ca0]; v1 = smem[(ro) + ca0 + 1];           \
            vc = smem[(ro) + cc];                                       \
            v3 = smem[(ro) + cb0]; v4 = smem[(ro) + cb0 + 1];           \
        }                                                               \
        const uint32_t* p0 = (const uint32_t*)&v0;                      \
        const uint32_t* p1 = (const uint32_t*)&v1;                      \
        const uint32_t* pc = (const uint32_t*)&vc;                      \
        const uint32_t* p3 = (const uint32_t*)&v3;                      \
        const uint32_t* p4 = (const uint32_t*)&v4;                      \
        _Pragma("unroll")                                               \
        for (int pp = 0; pp < 4; ++pp) {                                \
            Av[pp] = lerp2(u2h(p0[pp]), u2h(p1[pp]), fxa2);             \
            Cv[pp] = u2h(pc[pp]);                                       \
            Bv[pp] = lerp2(u2h(p3[pp]), u2h(p4[pp]), fxb2);             \
        } } while (0)

        __half2 t0[4], t1[4], t2[4];
        // ky = 0 : rows ra0 (always), ra0+1 (weight fya -> masked) lerped by fya
        LOADCOLS(ra0 * RDJ, 1, A0, C0, B0);
        LOADCOLS((ra0 + 1) * RDJ, 0, A1, C1, B1);
        #pragma unroll
        for (int pp = 0; pp < 4; ++pp) {
            __half2 SA = lerp2(A0[pp], A1[pp], fya2);
            __half2 SC = lerp2(C0[pp], C1[pp], fya2);
            __half2 SB = lerp2(B0[pp], B1[pp], fya2);
            t0[pp] = __hmul2(d2[pp][0], SA);
            t0[pp] = __hfma2(d2[pp][1], SC, t0[pp]);
            t0[pp] = __hfma2(d2[pp][2], SB, t0[pp]);
        }
        // ky = 1 : exact center row (always)
        LOADCOLS(rc * RDJ, 1, A0, C0, B0);
        #pragma unroll
        for (int pp = 0; pp < 4; ++pp) {
            t1[pp] = __hmul2(d2[pp][3], A0[pp]);
            t1[pp] = __hfma2(d2[pp][4], C0[pp], t1[pp]);
            t1[pp] = __hfma2(d2[pp][5], B0[pp], t1[pp]);
        }
        // ky = 2 : rows rb0 (always), rb0+1 (weight fyb -> masked) lerped by fyb
        LOADCOLS(rb0 * RDJ, 1, A0, C0, B0);
        LOADCOLS((rb0 + 1) * RDJ, 0, A1, C1, B1);
        #pragma unroll
        for (int pp = 0; pp < 4; ++pp) {
            __half2 SA = lerp2(A0[pp], A1[pp], fyb2);
            __half2 SC = lerp2(C0[pp], C1[pp], fyb2);
            __half2 SB = lerp2(B0[pp], B1[pp], fyb2);
            t2[pp] = __hmul2(d2[pp][6], SA);
            t2[pp] = __hfma2(d2[pp][7], SC, t2[pp]);
            t2[pp] = __hfma2(d2[pp][8], SB, t2[pp]);
        }
#undef LOADCOLS

        const size_t ob = ((size_t)n * 64 + c0) * HW_ + gi * W_ + gj;
        #pragma unroll
        for (int pp = 0; pp < 4; ++pp) {
            __half2 acc = __hadd2(__hadd2(t0[pp], t1[pp]), t2[pp]);
            out[ob + (size_t)(2 * pp) * HW_]     = __low2float(acc);
            out[ob + (size_t)(2 * pp + 1) * HW_] = __high2float(acc);
        }
    }
}

extern "C" void kernel_launch(void* const* d_in, const int* in_sizes, int n_in,
                              void* d_out, int out_size, void* d_ws, size_t ws_size,
                              hipStream_t stream) {
    const float* x    = (const float*)d_in[0];
    const float* pw   = (const float*)d_in[1];
    const float* offw = (const float*)d_in[2];
    const float* offb = (const float*)d_in[3];
    const float* dwp  = (const float*)d_in[4];

    uint32_t* ypackI = (uint32_t*)d_ws;                                 // 64 MiB
    float* sbuf = (float*)((char*)d_ws + (size_t)NIMG * 8 * HW_ * 16);  // 2 MiB
    float* out  = (float*)d_out;

    hipLaunchKernelGGL(pw_off_kernel, dim3(2048), dim3(256), 0, stream,
                       x, pw, offw, offb, ypackI, sbuf);
    hipLaunchKernelGGL(deform_kernel, dim3(2048), dim3(512), 0, stream,
                       (const uint4*)ypackI, sbuf, dwp, out);
}

// Round 3
// 284.298 us; speedup vs baseline: 1.0682x; 1.0682x over previous
//
#include <hip/hip_runtime.h>
#include <hip/hip_fp16.h>
#include <stdint.h>

#define H_   256
#define W_   256
#define HW_  65536
#define NIMG 8

#define TI   32
#define TJ   64
#define HALO 10
#define RDI  52   // TI + 2*HALO
#define RDJ  84   // TJ + 2*HALO

typedef _Float16 half8_t __attribute__((ext_vector_type(8)));
typedef __fp16   fp16x2  __attribute__((ext_vector_type(2)));
typedef float    float4_t __attribute__((ext_vector_type(4)));

__device__ __forceinline__ uint32_t pk2(float a, float b) {
    fp16x2 h = __builtin_amdgcn_cvt_pkrtz(a, b);
    union { fp16x2 h; uint32_t u; } v; v.h = h; return v.u;
}
__device__ __forceinline__ __half2 u2h(uint32_t u) {
    union { uint32_t u; __half2 h; } v; v.u = u; return v.h;
}
__device__ __forceinline__ __half2 lerp2(__half2 p, __half2 q, __half2 f) {
    return __hfma2(f, __hsub2(q, p), p);
}

// ---------------- Kernel A: pointwise conv via MFMA f16, direct global loads ----------------
// v2: 2-deep software-pipelined x loads — raw floats for j+1 issue before the
// pack/MFMA/epilogue of j, hiding ~900cy HBM latency under the compute phase (T14).
__global__ __launch_bounds__(256) void pw_off_kernel(
    const float* __restrict__ x, const float* __restrict__ pw,
    const float* __restrict__ offw, const float* __restrict__ offb,
    uint32_t* __restrict__ ypackI, float* __restrict__ sbuf)
{
    const int t    = threadIdx.x;
    const int blk  = blockIdx.x;          // 2048 blocks, 256 px each
    const int n    = blk >> 8;
    const int hw0  = (blk & 255) << 8;
    const int lane = t & 63;
    const int l15  = lane & 15;
    const int q    = lane >> 4;
    const int wv   = t >> 6;

    half8_t af[4][2];
    #pragma unroll
    for (int mt = 0; mt < 4; ++mt) {
        #pragma unroll
        for (int kt = 0; kt < 2; ++kt) {
            const float* wr = pw + (mt * 16 + l15) * 64 + kt * 32 + q * 8;
            float4 w0 = *(const float4*)wr;
            float4 w1 = *(const float4*)(wr + 4);
            union { uint32_t u[4]; half8_t h; } v;
            v.u[0] = pk2(w0.x, w0.y); v.u[1] = pk2(w0.z, w0.w);
            v.u[2] = pk2(w1.x, w1.y); v.u[3] = pk2(w1.z, w1.w);
            af[mt][kt] = v.h;
        }
    }
    float4_t ow4[4];
    #pragma unroll
    for (int mt = 0; mt < 4; ++mt)
        ow4[mt] = *(const float4_t*)(offw + mt * 16 + q * 4);
    const float bias = offb[0];

    const float* xbase = x + (size_t)n * 64 * HW_;

    float rv[2][16];
#define ISSUE(jj, buf) do {                                              \
        const int pix_ = (wv * 4 + (jj)) * 16 + l15;                     \
        const float* xp_ = xbase + hw0 + pix_;                           \
        _Pragma("unroll")                                                \
        for (int kt_ = 0; kt_ < 2; ++kt_) {                              \
            const float* xk_ = xp_ + (size_t)(kt_ * 32 + q * 8) * HW_;   \
            _Pragma("unroll")                                            \
            for (int c_ = 0; c_ < 8; ++c_)                               \
                rv[buf][kt_ * 8 + c_] = xk_[(size_t)c_ * HW_];           \
        } } while (0)

    ISSUE(0, 0);

    #pragma unroll
    for (int j = 0; j < 4; ++j) {
        if (j < 3) ISSUE(j + 1, (j + 1) & 1);   // prefetch next pixel-group

        const int jb  = j & 1;
        const int pix = (wv * 4 + j) * 16 + l15;
        const int hw  = hw0 + pix;

        half8_t bf[2];
        #pragma unroll
        for (int kt = 0; kt < 2; ++kt) {
            union { uint32_t u[4]; half8_t h; } vv;
            vv.u[0] = pk2(rv[jb][kt * 8 + 0], rv[jb][kt * 8 + 1]);
            vv.u[1] = pk2(rv[jb][kt * 8 + 2], rv[jb][kt * 8 + 3]);
            vv.u[2] = pk2(rv[jb][kt * 8 + 4], rv[jb][kt * 8 + 5]);
            vv.u[3] = pk2(rv[jb][kt * 8 + 6], rv[jb][kt * 8 + 7]);
            bf[kt] = vv.h;
        }

        float4_t acc[4] = {{0,0,0,0},{0,0,0,0},{0,0,0,0},{0,0,0,0}};
        #pragma unroll
        for (int kt = 0; kt < 2; ++kt) {
            #pragma unroll
            for (int mt = 0; mt < 4; ++mt)
                acc[mt] = __builtin_amdgcn_mfma_f32_16x16x32_f16(af[mt][kt], bf[kt], acc[mt], 0, 0, 0);
        }

        float sp = 0.f;
        #pragma unroll
        for (int mt = 0; mt < 4; ++mt)
            sp += acc[mt][0] * ow4[mt][0] + acc[mt][1] * ow4[mt][1]
                + acc[mt][2] * ow4[mt][2] + acc[mt][3] * ow4[mt][3];
        sp += __shfl_xor(sp, 16, 64);
        sp += __shfl_xor(sp, 32, 64);
        float sv = fminf(fmaxf(sp + bias, 0.f), 8.f);
        if (q == 0) sbuf[(size_t)n * HW_ + hw] = sv;

        #pragma unroll
        for (int mt = 0; mt < 4; ++mt) {
            uint2 st;
            st.x = pk2(acc[mt][0], acc[mt][1]);
            st.y = pk2(acc[mt][2], acc[mt][3]);
            const int pg = mt * 2 + (q >> 1);
            size_t ad = (((size_t)(n * 8 + pg)) * HW_ + hw) * 4 + (q & 1) * 2;
            *(uint2*)&ypackI[ad] = st;
        }
    }
#undef ISSUE
}

// ---------------- Kernel B: deformable depthwise 3x3, separable bilinear ----------------
// Exact R1 version (measured fastest): 32x64 tile, 512 threads, split-phase staging.
__global__ __launch_bounds__(512) void deform_kernel(
    const uint4* __restrict__ ypackI, const float* __restrict__ sbuf,
    const float* __restrict__ dwp, float* __restrict__ out)
{
    __shared__ uint4 smem[RDI * RDJ];   // 69.9 KB -> 2 blocks/CU

    const int t  = threadIdx.x;
    const int tj = blockIdx.x;   // 0..3
    const int ti = blockIdx.y;   // 0..7
    const int z  = blockIdx.z;   // n*8 + pg
    const int n  = z >> 3;
    const int pg = z & 7;
    const int i0 = ti * TI, j0 = tj * TJ;

    // ---- stage zero-padded interleaved region: issue-early / write-late ----
    const size_t ybase = (size_t)z * HW_;
    uint4 vst[9];
    #pragma unroll
    for (int u = 0; u < 9; ++u) {
        const int idx = t + u * 512;
        uint4 v = {0u, 0u, 0u, 0u};
        if (u < 8 || t < RDI * RDJ - 8 * 512) {     // 4368 total
            int r  = idx / RDJ;
            int c  = idx - r * RDJ;
            int gr = i0 - HALO + r;
            int gc = j0 - HALO + c;
            bool ok = (gr >= 0) & (gr < H_) & (gc >= 0) & (gc < W_);
            if (ok) v = ypackI[ybase + gr * W_ + gc];
        }
        vst[u] = v;
    }
    #pragma unroll
    for (int u = 0; u < 9; ++u) {
        const int idx = t + u * 512;
        if (u < 8 || t < RDI * RDJ - 8 * 512)
            smem[idx] = vst[u];
    }

    // depthwise weights (uniform scalar loads), packed per channel-pair
    const int c0 = pg * 8;
    __half2 d2[4][9];
    #pragma unroll
    for (int pp = 0; pp < 4; ++pp) {
        #pragma unroll
        for (int k = 0; k < 9; ++k)
            d2[pp][k] = __floats2half2_rn(dwp[(c0 + 2 * pp) * 9 + k],
                                          dwp[(c0 + 2 * pp + 1) * 9 + k]);
    }
    __syncthreads();

    const int lj = t & 63;      // column within tile 0..63
    const int l8 = t >> 6;      // wave row 0..7

    #pragma unroll
    for (int qq = 0; qq < 4; ++qq) {
        const int li = l8 + qq * 8;           // 0..31
        const int gi = i0 + li, gj = j0 + lj;
        const float sv = sbuf[(size_t)n * HW_ + gi * W_ + gj];
        const float tt = 1.0f + sv;
        const float lr = (float)(li + HALO);
        const float lc = (float)(lj + HALO);
        const int ra0 = (int)floorf(lr - tt); const float fya = (lr - tt) - (float)ra0;
        const int rb0 = (int)floorf(lr + tt); const float fyb = (lr + tt) - (float)rb0;
        const int ca0 = (int)floorf(lc - tt); const float fxa = (lc - tt) - (float)ca0;
        const int cb0 = (int)floorf(lc + tt); const float fxb = (lc + tt) - (float)cb0;
        const int rc = li + HALO, cc = lj + HALO;
        const __half2 fxa2 = __float2half2_rn(fxa);
        const __half2 fxb2 = __float2half2_rn(fxb);
        const __half2 fya2 = __float2half2_rn(fya);
        const __half2 fyb2 = __float2half2_rn(fyb);

        __half2 A0[4], C0[4], B0[4], A1[4], C1[4], B1[4];

#define LOADCOLS(ro, Av, Cv, Bv) do {                                   \
        uint4 v0 = smem[(ro) + ca0]; uint4 v1 = smem[(ro) + ca0 + 1];   \
        uint4 vc = smem[(ro) + cc];                                     \
        uint4 v3 = smem[(ro) + cb0]; uint4 v4 = smem[(ro) + cb0 + 1];   \
        const uint32_t* p0 = (const uint32_t*)&v0;                      \
        const uint32_t* p1 = (const uint32_t*)&v1;                      \
        const uint32_t* pc = (const uint32_t*)&vc;                      \
        const uint32_t* p3 = (const uint32_t*)&v3;                      \
        const uint32_t* p4 = (const uint32_t*)&v4;                      \
        _Pragma("unroll")                                               \
        for (int pp = 0; pp < 4; ++pp) {                                \
            Av[pp] = lerp2(u2h(p0[pp]), u2h(p1[pp]), fxa2);             \
            Cv[pp] = u2h(pc[pp]);                                       \
            Bv[pp] = lerp2(u2h(p3[pp]), u2h(p4[pp]), fxb2);             \
        } } while (0)

        __half2 acc[4];
        // ky = 0 : rows ra0, ra0+1 lerped by fya
        LOADCOLS(ra0 * RDJ, A0, C0, B0);
        LOADCOLS((ra0 + 1) * RDJ, A1, C1, B1);
        #pragma unroll
        for (int pp = 0; pp < 4; ++pp) {
            __half2 SA = lerp2(A0[pp], A1[pp], fya2);
            __half2 SC = lerp2(C0[pp], C1[pp], fya2);
            __half2 SB = lerp2(B0[pp], B1[pp], fya2);
            acc[pp] = __hmul2(d2[pp][0], SA);
            acc[pp] = __hfma2(d2[pp][1], SC, acc[pp]);
            acc[pp] = __hfma2(d2[pp][2], SB, acc[pp]);
        }
        // ky = 1 : exact center row
        LOADCOLS(rc * RDJ, A0, C0, B0);
        #pragma unroll
        for (int pp = 0; pp < 4; ++pp) {
            acc[pp] = __hfma2(d2[pp][3], A0[pp], acc[pp]);
            acc[pp] = __hfma2(d2[pp][4], C0[pp], acc[pp]);
            acc[pp] = __hfma2(d2[pp][5], B0[pp], acc[pp]);
        }
        // ky = 2 : rows rb0, rb0+1 lerped by fyb
        LOADCOLS(rb0 * RDJ, A0, C0, B0);
        LOADCOLS((rb0 + 1) * RDJ, A1, C1, B1);
        #pragma unroll
        for (int pp = 0; pp < 4; ++pp) {
            __half2 SA = lerp2(A0[pp], A1[pp], fyb2);
            __half2 SC = lerp2(C0[pp], C1[pp], fyb2);
            __half2 SB = lerp2(B0[pp], B1[pp], fyb2);
            acc[pp] = __hfma2(d2[pp][6], SA, acc[pp]);
            acc[pp] = __hfma2(d2[pp][7], SC, acc[pp]);
            acc[pp] = __hfma2(d2[pp][8], SB, acc[pp]);
        }
#undef LOADCOLS

        const size_t ob = ((size_t)n * 64 + c0) * HW_ + gi * W_ + gj;
        #pragma unroll
        for (int pp = 0; pp < 4; ++pp) {
            out[ob + (size_t)(2 * pp) * HW_]     = __low2float(acc[pp]);
            out[ob + (size_t)(2 * pp + 1) * HW_] = __high2float(acc[pp]);
        }
    }
}

extern "C" void kernel_launch(void* const* d_in, const int* in_sizes, int n_in,
                              void* d_out, int out_size, void* d_ws, size_t ws_size,
                              hipStream_t stream) {
    const float* x    = (const float*)d_in[0];
    const float* pw   = (const float*)d_in[1];
    const float* offw = (const float*)d_in[2];
    const float* offb = (const float*)d_in[3];
    const float* dwp  = (const float*)d_in[4];

    uint32_t* ypackI = (uint32_t*)d_ws;                                 // 64 MiB
    float* sbuf = (float*)((char*)d_ws + (size_t)NIMG * 8 * HW_ * 16);  // 2 MiB
    float* out  = (float*)d_out;

    hipLaunchKernelGGL(pw_off_kernel, dim3(2048), dim3(256), 0, stream,
                       x, pw, offw, offb, ypackI, sbuf);
    hipLaunchKernelGGL(deform_kernel, dim3(4, 8, NIMG * 8), dim3(512), 0, stream,
                       (const uint4*)ypackI, sbuf, dwp, out);
}